// Round 1
// baseline (374.249 us; speedup 1.0000x reference)
//
#include <hip/hip_runtime.h>
#include <hip/hip_fp16.h>

// GCN 2-layer -- r16 restructure of the edge pipeline.
// Previous best (206 us): k_part (bucket LDS hist + packed scatter) ->
// k_bsort (re-read packed, LDS counting sort) -> k_gemm -> k_fused48 -> k_agg.
// This version replaces {k_part, k_bsort, standalone k_gemm} with a direct
// global counting sort at (bucket, dst_local, src_chunk) key granularity:
//   k_hist:  1 pass over edges, atomicAdd into 800k-counter hist (3.2 MB).
//   k_scan:  per-bucket 1024-key scan (same proven scan as old k_bsort),
//            emits rowinfo/dinv, writes exclusive prefixes back as cursors.
//   k_scatgemm: merged grid -- blocks [0,782) scatter edges DIRECTLY to their
//            final sorted srcsort slot (atomic cursor), blocks [782,1564) run
//            the unchanged register-tiled GEMM1 (dinv ready after k_scan).
//            Independent phases, all blocks co-resident => true overlap
//            (unlike r16 fat-merge, which fused DEPENDENT phases).
// The packed[] 13 MB round trip + 2x full LDS re-sort disappear; srcsort /
// rowinfo / dinv semantics are bit-identical, so the two proven-at-floor
// aggregation kernels (k_fused48 44us @ 2.33 TB/s compulsory 8-XCD sweep;
// k_agg) are byte-for-byte untouched.
// out = GCNConv(relu(GCNConv(x,W1,b1)), W2, b2); N=100k, E=1.6M, 64->48->32.

#define NN 100000
#define NE 1600000
#define NPB 128                         // nodes per bucket
#define NBUCK ((NN + NPB - 1) / NPB)    // 782
#define PBITS 17                        // src fits in 17 bits
#define PMASK ((1 << PBITS) - 1)
#define CHB 3                           // log2 src chunks
#define CHS 14                          // chunk = src >> 14
#define NKEY (NPB << CHB)               // 1024 sort keys per bucket
#define CAP 4096                        // static slots per bucket (45-sigma)
#define UN 8                            // agg edge-loop unroll (masked batches)
#define EPT 8                           // edges per thread in hist/scatter
#define SCAT_G ((NE + 256 * EPT - 1) / (256 * EPT))   // 782
#define GB NBUCK                        // 782 gemm/fused blocks

struct alignas(8)  half4 { __half2 lo, hi; };
struct alignas(16) half8 { __half2 a, b, c, d; };

__device__ __forceinline__ int edge_key(int s, int d) {
    return ((d >> 7) << 10) | ((d & (NPB - 1)) << CHB) | (s >> CHS);
}

// Pass 1: full-granularity histogram. 1.6M no-return atomics spread over
// 800k counters (avg 2 hits each) -- negligible same-address contention.
__global__ __launch_bounds__(256) void
k_hist(const int* __restrict__ src, const int* __restrict__ dst,
       int* __restrict__ hist) {
    int base = blockIdx.x * (256 * EPT) + threadIdx.x * EPT;
    if (base >= NE) return;               // NE % 8 == 0: full batches only
    int4 s0 = *(const int4*)(src + base);
    int4 s1 = *(const int4*)(src + base + 4);
    int4 d0 = *(const int4*)(dst + base);
    int4 d1 = *(const int4*)(dst + base + 4);
    int ss[8] = {s0.x, s0.y, s0.z, s0.w, s1.x, s1.y, s1.z, s1.w};
    int dd[8] = {d0.x, d0.y, d0.z, d0.w, d1.x, d1.y, d1.z, d1.w};
#pragma unroll
    for (int u = 0; u < 8; ++u)
        atomicAdd(&hist[edge_key(ss[u], dd[u])], 1);
}

// Pass 2: per-bucket scan of 1024 keys (proven k_bsort scan), emits
// rowinfo = (global_start << 10) | deg, dinv = rsqrt(deg+1), and rewrites
// hist in place as global scatter cursors (bucket base b*CAP + prefix).
__global__ __launch_bounds__(256) void
k_scan(int* __restrict__ hist, unsigned int* __restrict__ rowinfo,
       float* __restrict__ dinv) {
    __shared__ int cnt[NKEY];
    __shared__ int tsum[256];
    int b = blockIdx.x, tid = threadIdx.x;
    int k0 = 4 * tid;
    int4 c = *(const int4*)&hist[(size_t)b * NKEY + k0];
    int loc = c.x + c.y + c.z + c.w;
    tsum[tid] = loc;
    __syncthreads();
    for (int off = 1; off < 256; off <<= 1) {
        int v = (tid >= off) ? tsum[tid - off] : 0;
        __syncthreads();
        tsum[tid] += v;
        __syncthreads();
    }
    int base = tsum[tid] - loc;
    cnt[k0]     = base;
    cnt[k0 + 1] = base + c.x;
    cnt[k0 + 2] = base + c.x + c.y;
    cnt[k0 + 3] = base + c.x + c.y + c.z;
    __syncthreads();
    int sz = tsum[255];
    if (tid < NPB) {
        int node = b * NPB + tid;
        if (node < NN) {
            int rs = cnt[tid << CHB];
            int re = (tid == NPB - 1) ? sz : cnt[(tid + 1) << CHB];
            rowinfo[node] = ((unsigned int)(b * CAP + rs) << 10) | (unsigned int)(re - rs);
            dinv[node] = rsqrtf((float)(re - rs + 1));   // +1 self-loop
        }
    }
    int e0 = b * CAP;
    int4 o = make_int4(e0 + cnt[k0], e0 + cnt[k0 + 1],
                       e0 + cnt[k0 + 2], e0 + cnt[k0 + 3]);
    *(int4*)&hist[(size_t)b * NKEY + k0] = o;
}

// Pass 3 (merged launch): blocks [0,SCAT_G) scatter edges to final sorted
// slots; blocks [SCAT_G, SCAT_G+GB) run GEMM1 (independent work, overlaps).
// GEMM1: Hh[M,48] = half( X[M,64] @ W1 * dinv[row] )  -- unchanged r15 code.
__global__ __launch_bounds__(256) void
k_scatgemm(const int* __restrict__ src, const int* __restrict__ dst,
           int* __restrict__ hist, int* __restrict__ srcsort,
           const float* __restrict__ X, const float* __restrict__ W1,
           const float* __restrict__ dinv, __half* __restrict__ Hh) {
    __shared__ float w[64 * 48];
    int tid = threadIdx.x;
    if (blockIdx.x < SCAT_G) {
        // ---- scatter ----
        int base = blockIdx.x * (256 * EPT) + tid * EPT;
        if (base >= NE) return;
        int4 s0 = *(const int4*)(src + base);
        int4 s1 = *(const int4*)(src + base + 4);
        int4 d0 = *(const int4*)(dst + base);
        int4 d1 = *(const int4*)(dst + base + 4);
        int ss[8] = {s0.x, s0.y, s0.z, s0.w, s1.x, s1.y, s1.z, s1.w};
        int dd[8] = {d0.x, d0.y, d0.z, d0.w, d1.x, d1.y, d1.z, d1.w};
#pragma unroll
        for (int u = 0; u < 8; ++u) {
            int p = atomicAdd(&hist[edge_key(ss[u], dd[u])], 1);
            srcsort[p] = ss[u];
        }
        return;
    }
    // ---- GEMM1 (register-tiled, 128 rows/block, 2x12 per thread) ----
    constexpr int NC = 48, CPT = 12, CG = 4, KF4 = 16;
    int R0 = (blockIdx.x - SCAT_G) * 128;
    for (int i = tid; i < 64 * 48; i += 256) w[i] = W1[i];
    __syncthreads();

    int tc = tid % CG, tr = tid / CG;
    int r0 = R0 + 2 * tr, r1 = r0 + 1;
    int c0 = tc * CPT;
    bool ok0 = r0 < NN, ok1 = r1 < NN;
    const float4* X4 = (const float4*)X;
    const float4 z4 = make_float4(0.f, 0.f, 0.f, 0.f);

    float acc[2][CPT];
#pragma unroll
    for (int rr = 0; rr < 2; ++rr)
#pragma unroll
        for (int j = 0; j < CPT; ++j) acc[rr][j] = 0.f;

#pragma unroll 2
    for (int k4 = 0; k4 < KF4; ++k4) {
        float4 xa = ok0 ? X4[(size_t)r0 * KF4 + k4] : z4;
        float4 xb = ok1 ? X4[(size_t)r1 * KF4 + k4] : z4;
        float ar[4] = {xa.x, xa.y, xa.z, xa.w};
        float br[4] = {xb.x, xb.y, xb.z, xb.w};
#pragma unroll
        for (int j = 0; j < 4; ++j) {
            float va = ar[j], vb = br[j];
#pragma unroll
            for (int q = 0; q < CPT / 4; ++q) {
                float4 wv = *(const float4*)&w[(4 * k4 + j) * NC + c0 + 4 * q];
                acc[0][q*4+0] = fmaf(va, wv.x, acc[0][q*4+0]);
                acc[0][q*4+1] = fmaf(va, wv.y, acc[0][q*4+1]);
                acc[0][q*4+2] = fmaf(va, wv.z, acc[0][q*4+2]);
                acc[0][q*4+3] = fmaf(va, wv.w, acc[0][q*4+3]);
                acc[1][q*4+0] = fmaf(vb, wv.x, acc[1][q*4+0]);
                acc[1][q*4+1] = fmaf(vb, wv.y, acc[1][q*4+1]);
                acc[1][q*4+2] = fmaf(vb, wv.z, acc[1][q*4+2]);
                acc[1][q*4+3] = fmaf(vb, wv.w, acc[1][q*4+3]);
            }
        }
    }
#pragma unroll
    for (int rr = 0; rr < 2; ++rr) {
        int gr = r0 + rr;
        if (gr >= NN) continue;
        float d = dinv[gr];
#pragma unroll
        for (int q = 0; q < CPT / 4; ++q) {
            __half2 p0 = __floats2half2_rn(acc[rr][q*4+0] * d, acc[rr][q*4+1] * d);
            __half2 p1 = __floats2half2_rn(acc[rr][q*4+2] * d, acc[rr][q*4+3] * d);
            half4 hv; hv.lo = p0; hv.hi = p1;
            *(half4*)(Hh + (size_t)gr * NC + c0 + 4 * q) = hv;
        }
    }
}

// Fused layer-1 aggregation + relu/b1 + GEMM2 + dinv. 128-row tile, 256 thr
// (r12 geometry). Masked full-width UN-batches. UNCHANGED (at compulsory
// 8-XCD fabric floor: 102.5 MB @ 2.33 TB/s).
__global__ __launch_bounds__(256) void
k_fused48(const __half* __restrict__ Hh, const unsigned int* __restrict__ rowinfo,
          const int* __restrict__ srcsort, const float* __restrict__ dinv,
          const float* __restrict__ b1, const float* __restrict__ W2,
          __half* __restrict__ Hh2) {
    constexpr int ROWS = 128, XS = 49;
    __shared__ float Xs[ROWS * XS];      // 25088 B
    __shared__ float w2[48 * 32];        // 6144 B
    __shared__ float bb[48];
    int tid = threadIdx.x;
    int R0 = blockIdx.x * ROWS;
    for (int i = tid; i < 48 * 32; i += 256) w2[i] = W2[i];
    if (tid < 48) bb[tid] = b1[tid];
    __syncthreads();

    // ---- phase 1: aggregate into Xs (3 (row,chunk) items per thread) ----
    for (int t = tid; t < ROWS * 6; t += 256) {
        int lr = t / 6, q = t - lr * 6;
        int r = R0 + lr;
        if (r >= NN) continue;
        half8 sv = *(const half8*)(Hh + (size_t)r * 48 + 8 * q);   // self-loop
        float2 f0 = __half22float2(sv.a), f1 = __half22float2(sv.b);
        float2 f2 = __half22float2(sv.c), f3 = __half22float2(sv.d);
        float a0 = f0.x, a1 = f0.y, a2 = f1.x, a3 = f1.y;
        float a4 = f2.x, a5 = f2.y, a6 = f3.x, a7 = f3.y;
        unsigned int rp = rowinfo[r];
        int e0 = rp >> 10, e1 = e0 + (int)(rp & 1023);
        for (int e = e0; e < e1; e += UN) {
            int ss[UN]; float ms[UN];
#pragma unroll
            for (int u = 0; u < UN; ++u) {
                int ee = e + u;
                bool ok = ee < e1;
                ss[u] = srcsort[ok ? ee : e0];
                ms[u] = ok ? 1.f : 0.f;
            }
            half8 vv[UN];
#pragma unroll
            for (int u = 0; u < UN; ++u)
                vv[u] = *(const half8*)(Hh + (size_t)ss[u] * 48 + 8 * q);
#pragma unroll
            for (int u = 0; u < UN; ++u) {
                float2 g0 = __half22float2(vv[u].a), g1 = __half22float2(vv[u].b);
                float2 g2 = __half22float2(vv[u].c), g3 = __half22float2(vv[u].d);
                float m = ms[u];
                a0 = fmaf(g0.x, m, a0); a1 = fmaf(g0.y, m, a1);
                a2 = fmaf(g1.x, m, a2); a3 = fmaf(g1.y, m, a3);
                a4 = fmaf(g2.x, m, a4); a5 = fmaf(g2.y, m, a5);
                a6 = fmaf(g3.x, m, a6); a7 = fmaf(g3.y, m, a7);
            }
        }
        float d = dinv[r];
        float* xr = &Xs[lr * XS + 8 * q];
        const float* bf = &bb[8 * q];
        xr[0] = fmaxf(fmaf(a0, d, bf[0]), 0.f);
        xr[1] = fmaxf(fmaf(a1, d, bf[1]), 0.f);
        xr[2] = fmaxf(fmaf(a2, d, bf[2]), 0.f);
        xr[3] = fmaxf(fmaf(a3, d, bf[3]), 0.f);
        xr[4] = fmaxf(fmaf(a4, d, bf[4]), 0.f);
        xr[5] = fmaxf(fmaf(a5, d, bf[5]), 0.f);
        xr[6] = fmaxf(fmaf(a6, d, bf[6]), 0.f);
        xr[7] = fmaxf(fmaf(a7, d, bf[7]), 0.f);
    }
    __syncthreads();

    // ---- phase 2: Xs[128,48] @ W2[48,32] -> Hh2 (fp16); 2 rows x 8 cols ----
    int tc = tid & 3, tr = tid >> 2;
    int r0l = 2 * tr, c0 = tc * 8;
    float acc[2][8];
#pragma unroll
    for (int rr = 0; rr < 2; ++rr)
#pragma unroll
        for (int j = 0; j < 8; ++j) acc[rr][j] = 0.f;
#pragma unroll 4
    for (int k = 0; k < 48; ++k) {
        float x0 = Xs[r0l * XS + k];
        float x1 = Xs[(r0l + 1) * XS + k];
        float4 wv0 = *(const float4*)&w2[k * 32 + c0];
        float4 wv1 = *(const float4*)&w2[k * 32 + c0 + 4];
        acc[0][0] = fmaf(x0, wv0.x, acc[0][0]); acc[0][1] = fmaf(x0, wv0.y, acc[0][1]);
        acc[0][2] = fmaf(x0, wv0.z, acc[0][2]); acc[0][3] = fmaf(x0, wv0.w, acc[0][3]);
        acc[0][4] = fmaf(x0, wv1.x, acc[0][4]); acc[0][5] = fmaf(x0, wv1.y, acc[0][5]);
        acc[0][6] = fmaf(x0, wv1.z, acc[0][6]); acc[0][7] = fmaf(x0, wv1.w, acc[0][7]);
        acc[1][0] = fmaf(x1, wv0.x, acc[1][0]); acc[1][1] = fmaf(x1, wv0.y, acc[1][1]);
        acc[1][2] = fmaf(x1, wv0.z, acc[1][2]); acc[1][3] = fmaf(x1, wv0.w, acc[1][3]);
        acc[1][4] = fmaf(x1, wv1.x, acc[1][4]); acc[1][5] = fmaf(x1, wv1.y, acc[1][5]);
        acc[1][6] = fmaf(x1, wv1.z, acc[1][6]); acc[1][7] = fmaf(x1, wv1.w, acc[1][7]);
    }
#pragma unroll
    for (int rr = 0; rr < 2; ++rr) {
        int gr = R0 + r0l + rr;
        if (gr >= NN) continue;
        float d = dinv[gr];
        __half2 p0 = __floats2half2_rn(acc[rr][0] * d, acc[rr][1] * d);
        __half2 p1 = __floats2half2_rn(acc[rr][2] * d, acc[rr][3] * d);
        __half2 p2 = __floats2half2_rn(acc[rr][4] * d, acc[rr][5] * d);
        __half2 p3 = __floats2half2_rn(acc[rr][6] * d, acc[rr][7] * d);
        half8 hv; hv.a = p0; hv.b = p1; hv.c = p2; hv.d = p3;
        *(half8*)(Hh2 + (size_t)gr * 32 + c0) = hv;
    }
}

// Layer-2 aggregation: out[i,:] = dinv[i]*(Hh2[i,:] + sum Hh2[src,:]) + b2
// Masked full-width UN-batches. UNCHANGED.
template <int NC>
__global__ void k_agg(const __half* __restrict__ Hh, const unsigned int* __restrict__ rowinfo,
                      const int* __restrict__ srcsort, const float* __restrict__ dinv,
                      const float* __restrict__ bias, float* __restrict__ out) {
    constexpr int Q = NC / 8;
    int idx = blockIdx.x * blockDim.x + threadIdx.x;
    if (idx >= NN * Q) return;
    int r = idx / Q, q = idx - r * Q;
    half8 sv = *(const half8*)(Hh + (size_t)r * NC + 8 * q);
    float2 f0 = __half22float2(sv.a), f1 = __half22float2(sv.b);
    float2 f2 = __half22float2(sv.c), f3 = __half22float2(sv.d);
    float a0 = f0.x, a1 = f0.y, a2 = f1.x, a3 = f1.y;
    float a4 = f2.x, a5 = f2.y, a6 = f3.x, a7 = f3.y;
    unsigned int rp = rowinfo[r];
    int e0 = rp >> 10, e1 = e0 + (int)(rp & 1023);
    for (int e = e0; e < e1; e += UN) {
        int ss[UN]; float ms[UN];
#pragma unroll
        for (int u = 0; u < UN; ++u) {
            int ee = e + u;
            bool ok = ee < e1;
            ss[u] = srcsort[ok ? ee : e0];
            ms[u] = ok ? 1.f : 0.f;
        }
        half8 vv[UN];
#pragma unroll
        for (int u = 0; u < UN; ++u)
            vv[u] = *(const half8*)(Hh + (size_t)ss[u] * NC + 8 * q);
#pragma unroll
        for (int u = 0; u < UN; ++u) {
            float2 g0 = __half22float2(vv[u].a), g1 = __half22float2(vv[u].b);
            float2 g2 = __half22float2(vv[u].c), g3 = __half22float2(vv[u].d);
            float m = ms[u];
            a0 = fmaf(g0.x, m, a0); a1 = fmaf(g0.y, m, a1);
            a2 = fmaf(g1.x, m, a2); a3 = fmaf(g1.y, m, a3);
            a4 = fmaf(g2.x, m, a4); a5 = fmaf(g2.y, m, a5);
            a6 = fmaf(g3.x, m, a6); a7 = fmaf(g3.y, m, a7);
        }
    }
    float d = dinv[r];
    const float4* b4 = (const float4*)bias;
    float4 bv0 = b4[2 * q], bv1 = b4[2 * q + 1];
    a0 = fmaf(a0, d, bv0.x); a1 = fmaf(a1, d, bv0.y);
    a2 = fmaf(a2, d, bv0.z); a3 = fmaf(a3, d, bv0.w);
    a4 = fmaf(a4, d, bv1.x); a5 = fmaf(a5, d, bv1.y);
    a6 = fmaf(a6, d, bv1.z); a7 = fmaf(a7, d, bv1.w);
    float4* o4 = (float4*)(out + (size_t)r * NC + 8 * q);
    o4[0] = make_float4(a0, a1, a2, a3);
    o4[1] = make_float4(a4, a5, a6, a7);
}

extern "C" void kernel_launch(void* const* d_in, const int* in_sizes, int n_in,
                              void* d_out, int out_size, void* d_ws, size_t ws_size,
                              hipStream_t stream) {
    const float* x  = (const float*)d_in[0];
    const int*   ei = (const int*)d_in[1];   // [2,NE] int32
    const float* W1 = (const float*)d_in[2];
    const float* b1 = (const float*)d_in[3];
    const float* W2 = (const float*)d_in[4];
    const float* b2 = (const float*)d_in[5];
    float* out = (float*)d_out;

    const int* src = ei;
    const int* dst = ei + NE;

    char* p = (char*)d_ws;
    auto take = [&](size_t elems) { void* q = p; p += ((elems * 4 + 255) & ~255ull); return q; };
    int*          hist    = (int*)take((size_t)NBUCK * NKEY);  // 3.2 MB
    unsigned int* rowinfo = (unsigned int*)take(NN);
    float*        dinv    = (float*)take(NN);
    int*          srcsort = (int*)take((size_t)NBUCK * CAP);   // bucket-padded
    __half*       Hh      = (__half*)take((size_t)NN * 24);    // NN*48 halves
    __half*       Hh2     = (__half*)take((size_t)NN * 16);    // NN*32 halves

    const int B = 256;
    // --- direct counting sort: hist -> scan -> scatter (+GEMM1 merged) ---
    hipMemsetAsync(hist, 0, (size_t)NBUCK * NKEY * sizeof(int), stream);
    k_hist<<<SCAT_G, 256, 0, stream>>>(src, dst, hist);
    k_scan<<<NBUCK, 256, 0, stream>>>(hist, rowinfo, dinv);
    k_scatgemm<<<SCAT_G + GB, 256, 0, stream>>>(src, dst, hist, srcsort, x, W1, dinv, Hh);
    // --- fused: layer-1 aggregation + relu/b1 + GEMM2 + dinv ---
    k_fused48<<<GB, 256, 0, stream>>>(Hh, rowinfo, srcsort, dinv, b1, W2, Hh2);
    // --- layer-2 aggregation (+b2) ---
    k_agg<32><<<(NN * 4 + B - 1) / B, B, 0, stream>>>(Hh2, rowinfo, srcsort, dinv, b2, out);
}

// Round 2
// 231.239 us; speedup vs baseline: 1.6184x; 1.6184x over previous
//
#include <hip/hip_runtime.h>
#include <hip/hip_fp16.h>

// GCN 2-layer -- r17: revert to proven r15 pipeline (206 us) + two repairs.
// r16 lesson (374 us regression): direct scatter to final sorted slots =
// 1.6M isolated 4B stores -> 120 MB of random 64B-line RMW at ~0.7 TB/s
// (~150 us). The k_part->packed->k_bsort round trip IS the write-locality
// optimization: k_part scatters ~cluster-sized runs, k_bsort's final
// scatter is a permutation inside a contiguous 16KB bucket window (full
// lines, no amplification). Keep it.
// Changes vs r15:
//  (1) k_part fattened: 256 thr x EPT 64 = 16384 edges/block, 98 blocks.
//      Per-(block,bucket) cluster 21B -> 84B; scatter amp ~21MB -> ~9MB.
//  (2) GEMM1 merged under k_part (independent block ranges in one launch).
//      Enabled by storing Hh UNSCALED (= half(x@W1)); dinv[src] is applied
//      per-edge in k_fused48 as the batch mask multiplier (dinv = 400KB,
//      L2-resident; load is at the same dep level as the Hh gather, so the
//      latency chain does not deepen). Self term gets x dinv[r] at load.
//      k_agg / GEMM2 epilogue untouched (Hh2 still pre-scaled by dinv[r]).
// Aggregation kernels remain at the measured fabric floor (fused48: 102.5MB
// = 8 XCDs x 2 lines/row x 100k rows, 2.5 TB/s random-line ceiling).
// out = GCNConv(relu(GCNConv(x,W1,b1)), W2, b2); N=100k, E=1.6M, 64->48->32.

#define NN 100000
#define NE 1600000
#define NPB 128                         // nodes per bucket
#define NBUCK ((NN + NPB - 1) / NPB)    // 782
#define PBITS 17                        // src fits in 17 bits
#define PMASK ((1 << PBITS) - 1)
#define CHB 3                           // log2 src chunks
#define CHS 14                          // chunk = src >> 14
#define NKEY (NPB << CHB)               // 1024 sort keys per bucket
#define CAP 4096                        // static slots per bucket (45-sigma)
#define UN 8                            // agg edge-loop unroll (masked batches)
#define PEPT 64                         // edges per thread in k_part branch
#define PART_G ((NE + 256 * PEPT - 1) / (256 * PEPT))   // 98
#define GB NBUCK                        // 782 gemm/fused blocks

struct alignas(8)  half4 { __half2 lo, hi; };
struct alignas(16) half8 { __half2 a, b, c, d; };

// Merged launch: blocks [0,PART_G) partition edges into static bucket slots
// (packed = src | dst_local<<PBITS); blocks [PART_G, PART_G+GB) run GEMM1
// Hh[M,48] = half( X[M,64] @ W1 )  -- UNSCALED, so no dependency on dinv.
__global__ __launch_bounds__(256) void
k_partgemm(const int* __restrict__ src, const int* __restrict__ dst,
           int* __restrict__ cursor, int* __restrict__ packed,
           const float* __restrict__ X, const float* __restrict__ W1,
           __half* __restrict__ Hh) {
    __shared__ int h[NBUCK];
    __shared__ int base_[NBUCK];
    __shared__ float w[64 * 48];
    int tid = threadIdx.x;

    if (blockIdx.x < PART_G) {
        // ---- edge partition (fat blocks: 16384 edges) ----
        for (int i = tid; i < NBUCK; i += 256) h[i] = 0;
        __syncthreads();
        int ebase = blockIdx.x * (256 * PEPT);
        for (int k = 0; k < PEPT; ++k) {
            int e = ebase + k * 256 + tid;
            if (e < NE) atomicAdd(&h[dst[e] >> 7], 1);
        }
        __syncthreads();
        for (int i = tid; i < NBUCK; i += 256) {
            int c = h[i];
            if (c) base_[i] = atomicAdd(&cursor[i], c);
            h[i] = 0;
        }
        __syncthreads();
        for (int k = 0; k < PEPT; ++k) {
            int e = ebase + k * 256 + tid;
            if (e < NE) {
                int d = dst[e];
                int b = d >> 7;
                int r = atomicAdd(&h[b], 1);
                packed[(size_t)b * CAP + base_[b] + r] = src[e] | ((d & (NPB - 1)) << PBITS);
            }
        }
        return;
    }

    // ---- GEMM1 (register-tiled, 128 rows/block, 2x12 per thread) ----
    constexpr int NC = 48, CPT = 12, CG = 4, KF4 = 16;
    int R0 = (blockIdx.x - PART_G) * 128;
    for (int i = tid; i < 64 * 48; i += 256) w[i] = W1[i];
    __syncthreads();

    int tc = tid % CG, tr = tid / CG;
    int r0 = R0 + 2 * tr, r1 = r0 + 1;
    int c0 = tc * CPT;
    bool ok0 = r0 < NN, ok1 = r1 < NN;
    const float4* X4 = (const float4*)X;
    const float4 z4 = make_float4(0.f, 0.f, 0.f, 0.f);

    float acc[2][CPT];
#pragma unroll
    for (int rr = 0; rr < 2; ++rr)
#pragma unroll
        for (int j = 0; j < CPT; ++j) acc[rr][j] = 0.f;

#pragma unroll 2
    for (int k4 = 0; k4 < KF4; ++k4) {
        float4 xa = ok0 ? X4[(size_t)r0 * KF4 + k4] : z4;
        float4 xb = ok1 ? X4[(size_t)r1 * KF4 + k4] : z4;
        float ar[4] = {xa.x, xa.y, xa.z, xa.w};
        float br[4] = {xb.x, xb.y, xb.z, xb.w};
#pragma unroll
        for (int j = 0; j < 4; ++j) {
            float va = ar[j], vb = br[j];
#pragma unroll
            for (int q = 0; q < CPT / 4; ++q) {
                float4 wv = *(const float4*)&w[(4 * k4 + j) * NC + c0 + 4 * q];
                acc[0][q*4+0] = fmaf(va, wv.x, acc[0][q*4+0]);
                acc[0][q*4+1] = fmaf(va, wv.y, acc[0][q*4+1]);
                acc[0][q*4+2] = fmaf(va, wv.z, acc[0][q*4+2]);
                acc[0][q*4+3] = fmaf(va, wv.w, acc[0][q*4+3]);
                acc[1][q*4+0] = fmaf(vb, wv.x, acc[1][q*4+0]);
                acc[1][q*4+1] = fmaf(vb, wv.y, acc[1][q*4+1]);
                acc[1][q*4+2] = fmaf(vb, wv.z, acc[1][q*4+2]);
                acc[1][q*4+3] = fmaf(vb, wv.w, acc[1][q*4+3]);
            }
        }
    }
#pragma unroll
    for (int rr = 0; rr < 2; ++rr) {
        int gr = r0 + rr;
        if (gr >= NN) continue;
#pragma unroll
        for (int q = 0; q < CPT / 4; ++q) {
            __half2 p0 = __floats2half2_rn(acc[rr][q*4+0], acc[rr][q*4+1]);
            __half2 p1 = __floats2half2_rn(acc[rr][q*4+2], acc[rr][q*4+3]);
            half4 hv; hv.lo = p0; hv.hi = p1;
            *(half4*)(Hh + (size_t)gr * NC + c0 + 4 * q) = hv;
        }
    }
}

// per-bucket counting sort by (dst_local, src_chunk) -> srcsort (bucket-padded),
// rowinfo = (global_start << 10) | deg, dinv = rsqrt(deg+1). UNCHANGED (r15).
__global__ void k_bsort(const int* __restrict__ packed, const int* __restrict__ cursor,
                        int* __restrict__ srcsort, unsigned int* __restrict__ rowinfo,
                        float* __restrict__ dinv) {
    __shared__ int stage[CAP];          // 16 KB (sz <= CAP always)
    __shared__ int cnt[NKEY];           // 4 KB
    __shared__ int tsum[256];
    int tid = threadIdx.x, b = blockIdx.x;
    int e0 = b * CAP, sz = cursor[b];
    for (int i = tid; i < NKEY; i += 256) cnt[i] = 0;
    __syncthreads();
    for (int i = tid; i < sz; i += 256) {
        int w = packed[e0 + i];
        stage[i] = w;
        int key = ((w >> PBITS) << CHB) | ((w & PMASK) >> CHS);
        atomicAdd(&cnt[key], 1);
    }
    __syncthreads();
    int k0 = tid * 4;
    int c0 = cnt[k0], c1 = cnt[k0 + 1], c2 = cnt[k0 + 2], c3 = cnt[k0 + 3];
    int loc = c0 + c1 + c2 + c3;
    tsum[tid] = loc;
    __syncthreads();
    for (int off = 1; off < 256; off <<= 1) {
        int v = (tid >= off) ? tsum[tid - off] : 0;
        __syncthreads();
        tsum[tid] += v;
        __syncthreads();
    }
    int base = tsum[tid] - loc;
    cnt[k0]     = base;
    cnt[k0 + 1] = base + c0;
    cnt[k0 + 2] = base + c0 + c1;
    cnt[k0 + 3] = base + c0 + c1 + c2;
    __syncthreads();
    if (tid < NPB) {
        int node = b * NPB + tid;
        int rs = cnt[tid << CHB];
        int re = (tid == NPB - 1) ? sz : cnt[(tid + 1) << CHB];
        if (node < NN) {
            rowinfo[node] = ((unsigned int)(e0 + rs) << 10) | (unsigned int)(re - rs);
            dinv[node] = rsqrtf((float)(re - rs + 1));   // +1 self-loop
        }
    }
    __syncthreads();
    for (int i = tid; i < sz; i += 256) {
        int w = stage[i];
        int key = ((w >> PBITS) << CHB) | ((w & PMASK) >> CHS);
        int p = atomicAdd(&cnt[key], 1);
        srcsort[e0 + p] = w & PMASK;
    }
}

// Fused layer-1 aggregation + relu/b1 + GEMM2 + dinv. 128-row tile, 256 thr
// (r12 geometry). Hh is now UNSCALED: per-edge dinv[src] is the mask
// multiplier (L2-resident 400KB array, same dep level as the Hh gather);
// self term scaled by dinv[r] at load. Otherwise identical to r15.
__global__ __launch_bounds__(256) void
k_fused48(const __half* __restrict__ Hh, const unsigned int* __restrict__ rowinfo,
          const int* __restrict__ srcsort, const float* __restrict__ dinv,
          const float* __restrict__ b1, const float* __restrict__ W2,
          __half* __restrict__ Hh2) {
    constexpr int ROWS = 128, XS = 49;
    __shared__ float Xs[ROWS * XS];      // 25088 B
    __shared__ float w2[48 * 32];        // 6144 B
    __shared__ float bb[48];
    int tid = threadIdx.x;
    int R0 = blockIdx.x * ROWS;
    for (int i = tid; i < 48 * 32; i += 256) w2[i] = W2[i];
    if (tid < 48) bb[tid] = b1[tid];
    __syncthreads();

    // ---- phase 1: aggregate into Xs (3 (row,chunk) items per thread) ----
    for (int t = tid; t < ROWS * 6; t += 256) {
        int lr = t / 6, q = t - lr * 6;
        int r = R0 + lr;
        if (r >= NN) continue;
        float dself = dinv[r];
        half8 sv = *(const half8*)(Hh + (size_t)r * 48 + 8 * q);   // self-loop
        float2 f0 = __half22float2(sv.a), f1 = __half22float2(sv.b);
        float2 f2 = __half22float2(sv.c), f3 = __half22float2(sv.d);
        float a0 = f0.x * dself, a1 = f0.y * dself;
        float a2 = f1.x * dself, a3 = f1.y * dself;
        float a4 = f2.x * dself, a5 = f2.y * dself;
        float a6 = f3.x * dself, a7 = f3.y * dself;
        unsigned int rp = rowinfo[r];
        int e0 = rp >> 10, e1 = e0 + (int)(rp & 1023);
        for (int e = e0; e < e1; e += UN) {
            int ss[UN]; float ms[UN];
#pragma unroll
            for (int u = 0; u < UN; ++u) {
                int ee = e + u;
                bool ok = ee < e1;
                ss[u] = srcsort[ok ? ee : e0];
                ms[u] = ok ? 1.f : 0.f;
            }
            half8 vv[UN]; float dv[UN];
#pragma unroll
            for (int u = 0; u < UN; ++u) {
                vv[u] = *(const half8*)(Hh + (size_t)ss[u] * 48 + 8 * q);
                dv[u] = dinv[ss[u]];
            }
#pragma unroll
            for (int u = 0; u < UN; ++u) {
                float2 g0 = __half22float2(vv[u].a), g1 = __half22float2(vv[u].b);
                float2 g2 = __half22float2(vv[u].c), g3 = __half22float2(vv[u].d);
                float m = ms[u] * dv[u];
                a0 = fmaf(g0.x, m, a0); a1 = fmaf(g0.y, m, a1);
                a2 = fmaf(g1.x, m, a2); a3 = fmaf(g1.y, m, a3);
                a4 = fmaf(g2.x, m, a4); a5 = fmaf(g2.y, m, a5);
                a6 = fmaf(g3.x, m, a6); a7 = fmaf(g3.y, m, a7);
            }
        }
        float d = dself;
        float* xr = &Xs[lr * XS + 8 * q];
        const float* bf = &bb[8 * q];
        xr[0] = fmaxf(fmaf(a0, d, bf[0]), 0.f);
        xr[1] = fmaxf(fmaf(a1, d, bf[1]), 0.f);
        xr[2] = fmaxf(fmaf(a2, d, bf[2]), 0.f);
        xr[3] = fmaxf(fmaf(a3, d, bf[3]), 0.f);
        xr[4] = fmaxf(fmaf(a4, d, bf[4]), 0.f);
        xr[5] = fmaxf(fmaf(a5, d, bf[5]), 0.f);
        xr[6] = fmaxf(fmaf(a6, d, bf[6]), 0.f);
        xr[7] = fmaxf(fmaf(a7, d, bf[7]), 0.f);
    }
    __syncthreads();

    // ---- phase 2: Xs[128,48] @ W2[48,32] -> Hh2 (fp16); 2 rows x 8 cols ----
    int tc = tid & 3, tr = tid >> 2;
    int r0l = 2 * tr, c0 = tc * 8;
    float acc[2][8];
#pragma unroll
    for (int rr = 0; rr < 2; ++rr)
#pragma unroll
        for (int j = 0; j < 8; ++j) acc[rr][j] = 0.f;
#pragma unroll 4
    for (int k = 0; k < 48; ++k) {
        float x0 = Xs[r0l * XS + k];
        float x1 = Xs[(r0l + 1) * XS + k];
        float4 wv0 = *(const float4*)&w2[k * 32 + c0];
        float4 wv1 = *(const float4*)&w2[k * 32 + c0 + 4];
        acc[0][0] = fmaf(x0, wv0.x, acc[0][0]); acc[0][1] = fmaf(x0, wv0.y, acc[0][1]);
        acc[0][2] = fmaf(x0, wv0.z, acc[0][2]); acc[0][3] = fmaf(x0, wv0.w, acc[0][3]);
        acc[0][4] = fmaf(x0, wv1.x, acc[0][4]); acc[0][5] = fmaf(x0, wv1.y, acc[0][5]);
        acc[0][6] = fmaf(x0, wv1.z, acc[0][6]); acc[0][7] = fmaf(x0, wv1.w, acc[0][7]);
        acc[1][0] = fmaf(x1, wv0.x, acc[1][0]); acc[1][1] = fmaf(x1, wv0.y, acc[1][1]);
        acc[1][2] = fmaf(x1, wv0.z, acc[1][2]); acc[1][3] = fmaf(x1, wv0.w, acc[1][3]);
        acc[1][4] = fmaf(x1, wv1.x, acc[1][4]); acc[1][5] = fmaf(x1, wv1.y, acc[1][5]);
        acc[1][6] = fmaf(x1, wv1.z, acc[1][6]); acc[1][7] = fmaf(x1, wv1.w, acc[1][7]);
    }
#pragma unroll
    for (int rr = 0; rr < 2; ++rr) {
        int gr = R0 + r0l + rr;
        if (gr >= NN) continue;
        float d = dinv[gr];
        __half2 p0 = __floats2half2_rn(acc[rr][0] * d, acc[rr][1] * d);
        __half2 p1 = __floats2half2_rn(acc[rr][2] * d, acc[rr][3] * d);
        __half2 p2 = __floats2half2_rn(acc[rr][4] * d, acc[rr][5] * d);
        __half2 p3 = __floats2half2_rn(acc[rr][6] * d, acc[rr][7] * d);
        half8 hv; hv.a = p0; hv.b = p1; hv.c = p2; hv.d = p3;
        *(half8*)(Hh2 + (size_t)gr * 32 + c0) = hv;
    }
}

// Layer-2 aggregation: out[i,:] = dinv[i]*(Hh2[i,:] + sum Hh2[src,:]) + b2
// Masked full-width UN-batches. UNCHANGED (Hh2 remains pre-scaled).
template <int NC>
__global__ void k_agg(const __half* __restrict__ Hh, const unsigned int* __restrict__ rowinfo,
                      const int* __restrict__ srcsort, const float* __restrict__ dinv,
                      const float* __restrict__ bias, float* __restrict__ out) {
    constexpr int Q = NC / 8;
    int idx = blockIdx.x * blockDim.x + threadIdx.x;
    if (idx >= NN * Q) return;
    int r = idx / Q, q = idx - r * Q;
    half8 sv = *(const half8*)(Hh + (size_t)r * NC + 8 * q);
    float2 f0 = __half22float2(sv.a), f1 = __half22float2(sv.b);
    float2 f2 = __half22float2(sv.c), f3 = __half22float2(sv.d);
    float a0 = f0.x, a1 = f0.y, a2 = f1.x, a3 = f1.y;
    float a4 = f2.x, a5 = f2.y, a6 = f3.x, a7 = f3.y;
    unsigned int rp = rowinfo[r];
    int e0 = rp >> 10, e1 = e0 + (int)(rp & 1023);
    for (int e = e0; e < e1; e += UN) {
        int ss[UN]; float ms[UN];
#pragma unroll
        for (int u = 0; u < UN; ++u) {
            int ee = e + u;
            bool ok = ee < e1;
            ss[u] = srcsort[ok ? ee : e0];
            ms[u] = ok ? 1.f : 0.f;
        }
        half8 vv[UN];
#pragma unroll
        for (int u = 0; u < UN; ++u)
            vv[u] = *(const half8*)(Hh + (size_t)ss[u] * NC + 8 * q);
#pragma unroll
        for (int u = 0; u < UN; ++u) {
            float2 g0 = __half22float2(vv[u].a), g1 = __half22float2(vv[u].b);
            float2 g2 = __half22float2(vv[u].c), g3 = __half22float2(vv[u].d);
            float m = ms[u];
            a0 = fmaf(g0.x, m, a0); a1 = fmaf(g0.y, m, a1);
            a2 = fmaf(g1.x, m, a2); a3 = fmaf(g1.y, m, a3);
            a4 = fmaf(g2.x, m, a4); a5 = fmaf(g2.y, m, a5);
            a6 = fmaf(g3.x, m, a6); a7 = fmaf(g3.y, m, a7);
        }
    }
    float d = dinv[r];
    const float4* b4 = (const float4*)bias;
    float4 bv0 = b4[2 * q], bv1 = b4[2 * q + 1];
    a0 = fmaf(a0, d, bv0.x); a1 = fmaf(a1, d, bv0.y);
    a2 = fmaf(a2, d, bv0.z); a3 = fmaf(a3, d, bv0.w);
    a4 = fmaf(a4, d, bv1.x); a5 = fmaf(a5, d, bv1.y);
    a6 = fmaf(a6, d, bv1.z); a7 = fmaf(a7, d, bv1.w);
    float4* o4 = (float4*)(out + (size_t)r * NC + 8 * q);
    o4[0] = make_float4(a0, a1, a2, a3);
    o4[1] = make_float4(a4, a5, a6, a7);
}

extern "C" void kernel_launch(void* const* d_in, const int* in_sizes, int n_in,
                              void* d_out, int out_size, void* d_ws, size_t ws_size,
                              hipStream_t stream) {
    const float* x  = (const float*)d_in[0];
    const int*   ei = (const int*)d_in[1];   // [2,NE] int32
    const float* W1 = (const float*)d_in[2];
    const float* b1 = (const float*)d_in[3];
    const float* W2 = (const float*)d_in[4];
    const float* b2 = (const float*)d_in[5];
    float* out = (float*)d_out;

    const int* src = ei;
    const int* dst = ei + NE;

    char* p = (char*)d_ws;
    auto take = [&](size_t elems) { void* q = p; p += ((elems * 4 + 255) & ~255ull); return q; };
    int*          cursor  = (int*)take(NBUCK);
    unsigned int* rowinfo = (unsigned int*)take(NN);
    float*        dinv    = (float*)take(NN);
    int*          srcsort = (int*)take((size_t)NBUCK * CAP);   // bucket-padded
    __half*       Hh      = (__half*)take((size_t)NN * 24);    // NN*48 halves
    int*          packed  = (int*)take((size_t)NBUCK * CAP);   // dead after bsort
    __half*       Hh2     = (__half*)packed;                   // reuse

    const int B = 256;
    // --- merged: edge partition (fat blocks) + GEMM1 (unscaled, no dep) ---
    hipMemsetAsync(cursor, 0, NBUCK * sizeof(int), stream);
    k_partgemm<<<PART_G + GB, 256, 0, stream>>>(src, dst, cursor, packed, x, W1, Hh);
    // --- per-bucket counting sort (writes rowinfo, dinv) ---
    k_bsort<<<NBUCK, 256, 0, stream>>>(packed, cursor, srcsort, rowinfo, dinv);
    // --- fused: layer-1 aggregation (per-edge dinv) + relu/b1 + GEMM2 ---
    k_fused48<<<GB, 256, 0, stream>>>(Hh, rowinfo, srcsort, dinv, b1, W2, Hh2);
    // --- layer-2 aggregation (+b2) ---
    k_agg<32><<<(NN * 4 + B - 1) / B, B, 0, stream>>>(Hh2, rowinfo, srcsort, dinv, b2, out);
}

// Round 4
// 205.880 us; speedup vs baseline: 1.8178x; 1.1232x over previous
//
#include <hip/hip_runtime.h>
#include <hip/hip_fp16.h>

// GCN 2-layer -- r18b: r15 pipeline with GEMM1 hidden under k_part.
// (r18 failed to build: missing `#define GB NBUCK` while k_fused48<<<GB,..>>>
//  -- restored here; logic otherwise identical.)
// Ledger of failed restructures (keep for future rounds):
//  r16 (374us): direct scatter to final sorted slot = 1.6M isolated 4B
//      stores -> 120MB random 64B-line RMW @ ~0.7TB/s. The part->packed->
//      bsort round trip IS the write-locality optimization. Never undo it.
//  r17 (231us): fat k_part blocks (98 x 256thr x EPT64) = 8x fewer waves,
//      8x longer chains -> latency-starved (Occ 11%, VALU 6%, hbm 5%).
//      k_part is LATENCY-bound, not BW-bound: wave count is the currency,
//      write amplification is irrelevant. 391 x 512 x EPT8 is the proven
//      operating point.
// r18 changes vs r15 (206us):
//  (1) GEMM1 merged into the k_part launch at 512 threads: blocks [0,391)
//      = exact r15 partition; blocks [391,782) = GEMM1, 256 rows each.
//      All 782 blocks co-resident (8 waves, 18.5KB LDS, ~56 VGPR -> 4
//      blocks/CU wave-limited) -> GEMM1's ~10us truly overlaps.
//  (2) (validated in r17, absmax bit-identical) Hh stored UNSCALED; dinv
//      applied per-edge in fused48 (dinv = 400KB, L2-resident, same dep
//      level as the Hh gather). Self term x dinv[r] at load. This is what
//      breaks the GEMM1 -> dinv -> bsort dependency and permits (1).
// fused48 (44us, 102.5MB @ 2.33TB/s 8-XCD compulsory sweep) and k_agg
// remain at the measured random-line fabric floor.
// out = GCNConv(relu(GCNConv(x,W1,b1)), W2, b2); N=100k, E=1.6M, 64->48->32.

#define NN 100000
#define NE 1600000
#define NPB 128                         // nodes per bucket
#define NBUCK ((NN + NPB - 1) / NPB)    // 782
#define PBITS 17                        // src fits in 17 bits
#define PMASK ((1 << PBITS) - 1)
#define CHB 3                           // log2 src chunks
#define CHS 14                          // chunk = src >> 14
#define NKEY (NPB << CHB)               // 1024 sort keys per bucket
#define CAP 4096                        // static slots per bucket (45-sigma)
#define UN 8                            // agg edge-loop unroll (masked batches)
#define PART_B 512
#define EPT 8                           // edges per thread (r15 proven)
#define PART_G ((NE + PART_B * EPT - 1) / (PART_B * EPT))   // 391
#define GROWS 256                       // rows per GEMM block (512 thr)
#define GEMM_G ((NN + GROWS - 1) / GROWS)                   // 391
#define GB NBUCK                        // fused48 / bsort grid (782)

struct alignas(8)  half4 { __half2 lo, hi; };
struct alignas(16) half8 { __half2 a, b, c, d; };

// Merged launch, 512 threads: blocks [0,PART_G) partition edges into static
// bucket slots (packed = src | dst_local<<PBITS) -- EXACT r15 geometry;
// blocks [PART_G, PART_G+GEMM_G) run GEMM1 Hh = half(X @ W1), UNSCALED.
__global__ __launch_bounds__(512) void
k_partgemm(const int* __restrict__ src, const int* __restrict__ dst,
           int* __restrict__ cursor, int* __restrict__ packed,
           const float* __restrict__ X, const float* __restrict__ W1,
           __half* __restrict__ Hh) {
    __shared__ int h[NBUCK];
    __shared__ int base_[NBUCK];
    __shared__ float w[64 * 48];
    int tid = threadIdx.x;

    if (blockIdx.x < PART_G) {
        // ---- edge partition (r15-proven: 4096 edges/block, chains of 8) ----
        for (int i = tid; i < NBUCK; i += PART_B) h[i] = 0;
        __syncthreads();
        int ebase = blockIdx.x * (PART_B * EPT);
        for (int k = 0; k < EPT; ++k) {
            int e = ebase + k * PART_B + tid;
            if (e < NE) atomicAdd(&h[dst[e] >> 7], 1);
        }
        __syncthreads();
        for (int i = tid; i < NBUCK; i += PART_B) {
            int c = h[i];
            if (c) base_[i] = atomicAdd(&cursor[i], c);
            h[i] = 0;
        }
        __syncthreads();
        for (int k = 0; k < EPT; ++k) {
            int e = ebase + k * PART_B + tid;
            if (e < NE) {
                int d = dst[e];
                int b = d >> 7;
                int r = atomicAdd(&h[b], 1);
                packed[(size_t)b * CAP + base_[b] + r] = src[e] | ((d & (NPB - 1)) << PBITS);
            }
        }
        return;
    }

    // ---- GEMM1 (register-tiled, 256 rows/block @512thr, 2x12 per thread) ----
    constexpr int NC = 48, CPT = 12, CG = 4, KF4 = 16;
    int R0 = (blockIdx.x - PART_G) * GROWS;
    for (int i = tid; i < 64 * 48; i += 512) w[i] = W1[i];
    __syncthreads();

    int tc = tid % CG, tr = tid / CG;          // tr in [0,128)
    int r0 = R0 + 2 * tr, r1 = r0 + 1;
    int c0 = tc * CPT;
    bool ok0 = r0 < NN, ok1 = r1 < NN;
    const float4* X4 = (const float4*)X;
    const float4 z4 = make_float4(0.f, 0.f, 0.f, 0.f);

    float acc[2][CPT];
#pragma unroll
    for (int rr = 0; rr < 2; ++rr)
#pragma unroll
        for (int j = 0; j < CPT; ++j) acc[rr][j] = 0.f;

#pragma unroll 2
    for (int k4 = 0; k4 < KF4; ++k4) {
        float4 xa = ok0 ? X4[(size_t)r0 * KF4 + k4] : z4;
        float4 xb = ok1 ? X4[(size_t)r1 * KF4 + k4] : z4;
        float ar[4] = {xa.x, xa.y, xa.z, xa.w};
        float br[4] = {xb.x, xb.y, xb.z, xb.w};
#pragma unroll
        for (int j = 0; j < 4; ++j) {
            float va = ar[j], vb = br[j];
#pragma unroll
            for (int q = 0; q < CPT / 4; ++q) {
                float4 wv = *(const float4*)&w[(4 * k4 + j) * NC + c0 + 4 * q];
                acc[0][q*4+0] = fmaf(va, wv.x, acc[0][q*4+0]);
                acc[0][q*4+1] = fmaf(va, wv.y, acc[0][q*4+1]);
                acc[0][q*4+2] = fmaf(va, wv.z, acc[0][q*4+2]);
                acc[0][q*4+3] = fmaf(va, wv.w, acc[0][q*4+3]);
                acc[1][q*4+0] = fmaf(vb, wv.x, acc[1][q*4+0]);
                acc[1][q*4+1] = fmaf(vb, wv.y, acc[1][q*4+1]);
                acc[1][q*4+2] = fmaf(vb, wv.z, acc[1][q*4+2]);
                acc[1][q*4+3] = fmaf(vb, wv.w, acc[1][q*4+3]);
            }
        }
    }
#pragma unroll
    for (int rr = 0; rr < 2; ++rr) {
        int gr = r0 + rr;
        if (gr >= NN) continue;
#pragma unroll
        for (int q = 0; q < CPT / 4; ++q) {
            __half2 p0 = __floats2half2_rn(acc[rr][q*4+0], acc[rr][q*4+1]);
            __half2 p1 = __floats2half2_rn(acc[rr][q*4+2], acc[rr][q*4+3]);
            half4 hv; hv.lo = p0; hv.hi = p1;
            *(half4*)(Hh + (size_t)gr * NC + c0 + 4 * q) = hv;
        }
    }
}

// per-bucket counting sort by (dst_local, src_chunk) -> srcsort (bucket-padded),
// rowinfo = (global_start << 10) | deg, dinv = rsqrt(deg+1). UNCHANGED (r15).
__global__ void k_bsort(const int* __restrict__ packed, const int* __restrict__ cursor,
                        int* __restrict__ srcsort, unsigned int* __restrict__ rowinfo,
                        float* __restrict__ dinv) {
    __shared__ int stage[CAP];          // 16 KB (sz <= CAP always)
    __shared__ int cnt[NKEY];           // 4 KB
    __shared__ int tsum[256];
    int tid = threadIdx.x, b = blockIdx.x;
    int e0 = b * CAP, sz = cursor[b];
    for (int i = tid; i < NKEY; i += 256) cnt[i] = 0;
    __syncthreads();
    for (int i = tid; i < sz; i += 256) {
        int w = packed[e0 + i];
        stage[i] = w;
        int key = ((w >> PBITS) << CHB) | ((w & PMASK) >> CHS);
        atomicAdd(&cnt[key], 1);
    }
    __syncthreads();
    int k0 = tid * 4;
    int c0 = cnt[k0], c1 = cnt[k0 + 1], c2 = cnt[k0 + 2], c3 = cnt[k0 + 3];
    int loc = c0 + c1 + c2 + c3;
    tsum[tid] = loc;
    __syncthreads();
    for (int off = 1; off < 256; off <<= 1) {
        int v = (tid >= off) ? tsum[tid - off] : 0;
        __syncthreads();
        tsum[tid] += v;
        __syncthreads();
    }
    int base = tsum[tid] - loc;
    cnt[k0]     = base;
    cnt[k0 + 1] = base + c0;
    cnt[k0 + 2] = base + c0 + c1;
    cnt[k0 + 3] = base + c0 + c1 + c2;
    __syncthreads();
    if (tid < NPB) {
        int node = b * NPB + tid;
        int rs = cnt[tid << CHB];
        int re = (tid == NPB - 1) ? sz : cnt[(tid + 1) << CHB];
        if (node < NN) {
            rowinfo[node] = ((unsigned int)(e0 + rs) << 10) | (unsigned int)(re - rs);
            dinv[node] = rsqrtf((float)(re - rs + 1));   // +1 self-loop
        }
    }
    __syncthreads();
    for (int i = tid; i < sz; i += 256) {
        int w = stage[i];
        int key = ((w >> PBITS) << CHB) | ((w & PMASK) >> CHS);
        int p = atomicAdd(&cnt[key], 1);
        srcsort[e0 + p] = w & PMASK;
    }
}

// Fused layer-1 aggregation + relu/b1 + GEMM2 + dinv. 128-row tile, 256 thr
// (r12 geometry). Hh UNSCALED: per-edge dinv[src] folded into the batch mask
// multiplier (validated r17, absmax bit-identical); self term x dinv[r].
__global__ __launch_bounds__(256) void
k_fused48(const __half* __restrict__ Hh, const unsigned int* __restrict__ rowinfo,
          const int* __restrict__ srcsort, const float* __restrict__ dinv,
          const float* __restrict__ b1, const float* __restrict__ W2,
          __half* __restrict__ Hh2) {
    constexpr int ROWS = 128, XS = 49;
    __shared__ float Xs[ROWS * XS];      // 25088 B
    __shared__ float w2[48 * 32];        // 6144 B
    __shared__ float bb[48];
    int tid = threadIdx.x;
    int R0 = blockIdx.x * ROWS;
    for (int i = tid; i < 48 * 32; i += 256) w2[i] = W2[i];
    if (tid < 48) bb[tid] = b1[tid];
    __syncthreads();

    // ---- phase 1: aggregate into Xs (3 (row,chunk) items per thread) ----
    for (int t = tid; t < ROWS * 6; t += 256) {
        int lr = t / 6, q = t - lr * 6;
        int r = R0 + lr;
        if (r >= NN) continue;
        float dself = dinv[r];
        half8 sv = *(const half8*)(Hh + (size_t)r * 48 + 8 * q);   // self-loop
        float2 f0 = __half22float2(sv.a), f1 = __half22float2(sv.b);
        float2 f2 = __half22float2(sv.c), f3 = __half22float2(sv.d);
        float a0 = f0.x * dself, a1 = f0.y * dself;
        float a2 = f1.x * dself, a3 = f1.y * dself;
        float a4 = f2.x * dself, a5 = f2.y * dself;
        float a6 = f3.x * dself, a7 = f3.y * dself;
        unsigned int rp = rowinfo[r];
        int e0 = rp >> 10, e1 = e0 + (int)(rp & 1023);
        for (int e = e0; e < e1; e += UN) {
            int ss[UN]; float ms[UN];
#pragma unroll
            for (int u = 0; u < UN; ++u) {
                int ee = e + u;
                bool ok = ee < e1;
                ss[u] = srcsort[ok ? ee : e0];
                ms[u] = ok ? 1.f : 0.f;
            }
            half8 vv[UN]; float dv[UN];
#pragma unroll
            for (int u = 0; u < UN; ++u) {
                vv[u] = *(const half8*)(Hh + (size_t)ss[u] * 48 + 8 * q);
                dv[u] = dinv[ss[u]];
            }
#pragma unroll
            for (int u = 0; u < UN; ++u) {
                float2 g0 = __half22float2(vv[u].a), g1 = __half22float2(vv[u].b);
                float2 g2 = __half22float2(vv[u].c), g3 = __half22float2(vv[u].d);
                float m = ms[u] * dv[u];
                a0 = fmaf(g0.x, m, a0); a1 = fmaf(g0.y, m, a1);
                a2 = fmaf(g1.x, m, a2); a3 = fmaf(g1.y, m, a3);
                a4 = fmaf(g2.x, m, a4); a5 = fmaf(g2.y, m, a5);
                a6 = fmaf(g3.x, m, a6); a7 = fmaf(g3.y, m, a7);
            }
        }
        float d = dself;
        float* xr = &Xs[lr * XS + 8 * q];
        const float* bf = &bb[8 * q];
        xr[0] = fmaxf(fmaf(a0, d, bf[0]), 0.f);
        xr[1] = fmaxf(fmaf(a1, d, bf[1]), 0.f);
        xr[2] = fmaxf(fmaf(a2, d, bf[2]), 0.f);
        xr[3] = fmaxf(fmaf(a3, d, bf[3]), 0.f);
        xr[4] = fmaxf(fmaf(a4, d, bf[4]), 0.f);
        xr[5] = fmaxf(fmaf(a5, d, bf[5]), 0.f);
        xr[6] = fmaxf(fmaf(a6, d, bf[6]), 0.f);
        xr[7] = fmaxf(fmaf(a7, d, bf[7]), 0.f);
    }
    __syncthreads();

    // ---- phase 2: Xs[128,48] @ W2[48,32] -> Hh2 (fp16); 2 rows x 8 cols ----
    int tc = tid & 3, tr = tid >> 2;
    int r0l = 2 * tr, c0 = tc * 8;
    float acc[2][8];
#pragma unroll
    for (int rr = 0; rr < 2; ++rr)
#pragma unroll
        for (int j = 0; j < 8; ++j) acc[rr][j] = 0.f;
#pragma unroll 4
    for (int k = 0; k < 48; ++k) {
        float x0 = Xs[r0l * XS + k];
        float x1 = Xs[(r0l + 1) * XS + k];
        float4 wv0 = *(const float4*)&w2[k * 32 + c0];
        float4 wv1 = *(const float4*)&w2[k * 32 + c0 + 4];
        acc[0][0] = fmaf(x0, wv0.x, acc[0][0]); acc[0][1] = fmaf(x0, wv0.y, acc[0][1]);
        acc[0][2] = fmaf(x0, wv0.z, acc[0][2]); acc[0][3] = fmaf(x0, wv0.w, acc[0][3]);
        acc[0][4] = fmaf(x0, wv1.x, acc[0][4]); acc[0][5] = fmaf(x0, wv1.y, acc[0][5]);
        acc[0][6] = fmaf(x0, wv1.z, acc[0][6]); acc[0][7] = fmaf(x0, wv1.w, acc[0][7]);
        acc[1][0] = fmaf(x1, wv0.x, acc[1][0]); acc[1][1] = fmaf(x1, wv0.y, acc[1][1]);
        acc[1][2] = fmaf(x1, wv0.z, acc[1][2]); acc[1][3] = fmaf(x1, wv0.w, acc[1][3]);
        acc[1][4] = fmaf(x1, wv1.x, acc[1][4]); acc[1][5] = fmaf(x1, wv1.y, acc[1][5]);
        acc[1][6] = fmaf(x1, wv1.z, acc[1][6]); acc[1][7] = fmaf(x1, wv1.w, acc[1][7]);
    }
#pragma unroll
    for (int rr = 0; rr < 2; ++rr) {
        int gr = R0 + r0l + rr;
        if (gr >= NN) continue;
        float d = dinv[gr];
        __half2 p0 = __floats2half2_rn(acc[rr][0] * d, acc[rr][1] * d);
        __half2 p1 = __floats2half2_rn(acc[rr][2] * d, acc[rr][3] * d);
        __half2 p2 = __floats2half2_rn(acc[rr][4] * d, acc[rr][5] * d);
        __half2 p3 = __floats2half2_rn(acc[rr][6] * d, acc[rr][7] * d);
        half8 hv; hv.a = p0; hv.b = p1; hv.c = p2; hv.d = p3;
        *(half8*)(Hh2 + (size_t)gr * 32 + c0) = hv;
    }
}

// Layer-2 aggregation: out[i,:] = dinv[i]*(Hh2[i,:] + sum Hh2[src,:]) + b2
// Masked full-width UN-batches. UNCHANGED (Hh2 remains pre-scaled).
template <int NC>
__global__ void k_agg(const __half* __restrict__ Hh, const unsigned int* __restrict__ rowinfo,
                      const int* __restrict__ srcsort, const float* __restrict__ dinv,
                      const float* __restrict__ bias, float* __restrict__ out) {
    constexpr int Q = NC / 8;
    int idx = blockIdx.x * blockDim.x + threadIdx.x;
    if (idx >= NN * Q) return;
    int r = idx / Q, q = idx - r * Q;
    half8 sv = *(const half8*)(Hh + (size_t)r * NC + 8 * q);
    float2 f0 = __half22float2(sv.a), f1 = __half22float2(sv.b);
    float2 f2 = __half22float2(sv.c), f3 = __half22float2(sv.d);
    float a0 = f0.x, a1 = f0.y, a2 = f1.x, a3 = f1.y;
    float a4 = f2.x, a5 = f2.y, a6 = f3.x, a7 = f3.y;
    unsigned int rp = rowinfo[r];
    int e0 = rp >> 10, e1 = e0 + (int)(rp & 1023);
    for (int e = e0; e < e1; e += UN) {
        int ss[UN]; float ms[UN];
#pragma unroll
        for (int u = 0; u < UN; ++u) {
            int ee = e + u;
            bool ok = ee < e1;
            ss[u] = srcsort[ok ? ee : e0];
            ms[u] = ok ? 1.f : 0.f;
        }
        half8 vv[UN];
#pragma unroll
        for (int u = 0; u < UN; ++u)
            vv[u] = *(const half8*)(Hh + (size_t)ss[u] * NC + 8 * q);
#pragma unroll
        for (int u = 0; u < UN; ++u) {
            float2 g0 = __half22float2(vv[u].a), g1 = __half22float2(vv[u].b);
            float2 g2 = __half22float2(vv[u].c), g3 = __half22float2(vv[u].d);
            float m = ms[u];
            a0 = fmaf(g0.x, m, a0); a1 = fmaf(g0.y, m, a1);
            a2 = fmaf(g1.x, m, a2); a3 = fmaf(g1.y, m, a3);
            a4 = fmaf(g2.x, m, a4); a5 = fmaf(g2.y, m, a5);
            a6 = fmaf(g3.x, m, a6); a7 = fmaf(g3.y, m, a7);
        }
    }
    float d = dinv[r];
    const float4* b4 = (const float4*)bias;
    float4 bv0 = b4[2 * q], bv1 = b4[2 * q + 1];
    a0 = fmaf(a0, d, bv0.x); a1 = fmaf(a1, d, bv0.y);
    a2 = fmaf(a2, d, bv0.z); a3 = fmaf(a3, d, bv0.w);
    a4 = fmaf(a4, d, bv1.x); a5 = fmaf(a5, d, bv1.y);
    a6 = fmaf(a6, d, bv1.z); a7 = fmaf(a7, d, bv1.w);
    float4* o4 = (float4*)(out + (size_t)r * NC + 8 * q);
    o4[0] = make_float4(a0, a1, a2, a3);
    o4[1] = make_float4(a4, a5, a6, a7);
}

extern "C" void kernel_launch(void* const* d_in, const int* in_sizes, int n_in,
                              void* d_out, int out_size, void* d_ws, size_t ws_size,
                              hipStream_t stream) {
    const float* x  = (const float*)d_in[0];
    const int*   ei = (const int*)d_in[1];   // [2,NE] int32
    const float* W1 = (const float*)d_in[2];
    const float* b1 = (const float*)d_in[3];
    const float* W2 = (const float*)d_in[4];
    const float* b2 = (const float*)d_in[5];
    float* out = (float*)d_out;

    const int* src = ei;
    const int* dst = ei + NE;

    char* p = (char*)d_ws;
    auto take = [&](size_t elems) { void* q = p; p += ((elems * 4 + 255) & ~255ull); return q; };
    int*          cursor  = (int*)take(NBUCK);
    unsigned int* rowinfo = (unsigned int*)take(NN);
    float*        dinv    = (float*)take(NN);
    int*          srcsort = (int*)take((size_t)NBUCK * CAP);   // bucket-padded
    __half*       Hh      = (__half*)take((size_t)NN * 24);    // NN*48 halves
    int*          packed  = (int*)take((size_t)NBUCK * CAP);   // dead after bsort
    __half*       Hh2     = (__half*)packed;                   // reuse

    const int B = 256;
    // --- merged: edge partition (r15 geometry) + GEMM1 (unscaled, no dep) ---
    hipMemsetAsync(cursor, 0, NBUCK * sizeof(int), stream);
    k_partgemm<<<PART_G + GEMM_G, 512, 0, stream>>>(src, dst, cursor, packed, x, W1, Hh);
    // --- per-bucket counting sort (writes rowinfo, dinv) ---
    k_bsort<<<NBUCK, 256, 0, stream>>>(packed, cursor, srcsort, rowinfo, dinv);
    // --- fused: layer-1 aggregation (per-edge dinv) + relu/b1 + GEMM2 ---
    k_fused48<<<GB, 256, 0, stream>>>(Hh, rowinfo, srcsort, dinv, b1, W2, Hh2);
    // --- layer-2 aggregation (+b2) ---
    k_agg<32><<<(NN * 4 + B - 1) / B, B, 0, stream>>>(Hh2, rowinfo, srcsort, dinv, b2, out);
}

// Round 5
// 200.499 us; speedup vs baseline: 1.8666x; 1.0268x over previous
//
#include <hip/hip_runtime.h>
#include <hip/hip_fp16.h>

// GCN 2-layer -- r19: kill the partition's random-RMW writes.
// Ledger (keep):
//  r16 (374us): direct scatter to final sorted slots = 1.6M isolated 4B
//      stores -> 120MB random 64B-line RMW @ ~0.7-0.8TB/s. Random WRITES
//      are the fabric's weak axis.
//  r17 (231us): fat k_part blocks = 8x fewer waves -> starved. Wave count
//      matters; but see r18b: the deeper truth is the write ceiling.
//  r18b (206us): GEMM1 merged under k_part at proven geometry: co-resident
//      but ZERO overlap -- partition is RMW-WRITE-BW-BOUND (37MB scatter @
//      0.8TB/s), so fabric was already saturated; gemm just added bytes.
//  Measured fabric ceilings: coalesced ~6TB/s; random-line READ ~2.4-2.5TB/s
//      (fused48); random partial-line WRITE ~0.8TB/s. Structure all passes
//      so random access lands on the READ side.
// r19: partition -> LDS-local counting sort per block, contiguous coalesced
//      16KB run out + seg[(blk,bucket)] = (start<<9)|count (all coalesced,
//      ZERO scattered writes). bsort2 gathers bucket b's 391 segments
//      (random-line READS ~25MB @ 2.4TB/s) then proceeds identically to the
//      proven bsort. GEMM1 stays merged (fabric now has headroom).
//      fused48/k_agg untouched (at the 2.33TB/s compulsory-sweep floor).
// out = GCNConv(relu(GCNConv(x,W1,b1)), W2, b2); N=100k, E=1.6M, 64->48->32.

#define NN 100000
#define NE 1600000
#define NPB 128                         // nodes per bucket
#define NBUCK ((NN + NPB - 1) / NPB)    // 782
#define PBITS 17                        // src fits in 17 bits
#define PMASK ((1 << PBITS) - 1)
#define CHB 3                           // log2 src chunks
#define CHS 14                          // chunk = src >> 14
#define NKEY (NPB << CHB)               // 1024 sort keys per bucket
#define CAP 4096                        // static slots per bucket (45-sigma)
#define UN 8                            // agg edge-loop unroll (masked batches)
#define PART_B 512
#define EPT 8                           // edges per thread
#define RUNW (PART_B * EPT)             // 4096 edges per partition block run
#define PART_G ((NE + RUNW - 1) / RUNW) // 391
#define GROWS 256                       // rows per GEMM block (512 thr)
#define GEMM_G ((NN + GROWS - 1) / GROWS)                   // 391
#define GB NBUCK                        // fused48 / bsort grid (782)

struct alignas(8)  half4 { __half2 lo, hi; };
struct alignas(16) half8 { __half2 a, b, c, d; };

// Merged launch, 512 threads.
// Blocks [0,PART_G): local counting sort of 4096 edges by bucket in LDS;
//   write contiguous run (coalesced 16KB) + seg word per (blk,bucket):
//   (local_start << 9) | count  (count<=~30, 9 bits is 45-sigma safe).
// Blocks [PART_G, PART_G+GEMM_G): GEMM1 Hh = half(X @ W1), UNSCALED.
__global__ __launch_bounds__(512) void
k_lsortgemm(const int* __restrict__ src, const int* __restrict__ dst,
            int* __restrict__ runs, unsigned int* __restrict__ seg,
            const float* __restrict__ X, const float* __restrict__ W1,
            __half* __restrict__ Hh) {
    __shared__ int h[NBUCK];          // count -> prefix -> cursor
    __shared__ int tsum[512];
    __shared__ int stage[RUNW];       // 16 KB
    __shared__ float w[64 * 48];      // 12 KB (gemm branch)
    int tid = threadIdx.x;

    if (blockIdx.x < PART_G) {
        for (int i = tid; i < NBUCK; i += PART_B) h[i] = 0;
        __syncthreads();
        int ebase = blockIdx.x * RUNW;
        int pw[EPT], pb[EPT];
#pragma unroll
        for (int k = 0; k < EPT; ++k) {
            int e = ebase + k * PART_B + tid;
            if (e < NE) {
                int d = dst[e];
                pb[k] = d >> 7;
                pw[k] = src[e] | ((d & (NPB - 1)) << PBITS);
                atomicAdd(&h[pb[k]], 1);
            } else pb[k] = -1;
        }
        __syncthreads();
        // scan 782 counters, 2 per thread (tid < 391)
        int c0 = 0, c1 = 0;
        if (tid < NBUCK / 2) { c0 = h[2 * tid]; c1 = h[2 * tid + 1]; }
        int loc = c0 + c1;
        tsum[tid] = (tid < NBUCK / 2) ? loc : 0;
        __syncthreads();
        for (int off = 1; off < 512; off <<= 1) {
            int v = (tid >= off) ? tsum[tid - off] : 0;
            __syncthreads();
            tsum[tid] += v;
            __syncthreads();
        }
        if (tid < NBUCK / 2) {
            int base = tsum[tid] - loc;
            seg[(size_t)blockIdx.x * NBUCK + 2 * tid]     = ((unsigned)base << 9) | (unsigned)c0;
            seg[(size_t)blockIdx.x * NBUCK + 2 * tid + 1] = ((unsigned)(base + c0) << 9) | (unsigned)c1;
            h[2 * tid]     = base;
            h[2 * tid + 1] = base + c0;
        }
        __syncthreads();
#pragma unroll
        for (int k = 0; k < EPT; ++k) {
            if (pb[k] >= 0) {
                int r = atomicAdd(&h[pb[k]], 1);
                stage[r] = pw[k];
            }
        }
        __syncthreads();
#pragma unroll
        for (int k = 0; k < EPT; ++k)
            runs[(size_t)blockIdx.x * RUNW + k * PART_B + tid] = stage[k * PART_B + tid];
        return;
    }

    // ---- GEMM1 (register-tiled, 256 rows/block @512thr, 2x12 per thread) ----
    constexpr int NC = 48, CPT = 12, CG = 4, KF4 = 16;
    int R0 = (blockIdx.x - PART_G) * GROWS;
    for (int i = tid; i < 64 * 48; i += 512) w[i] = W1[i];
    __syncthreads();

    int tc = tid % CG, tr = tid / CG;          // tr in [0,128)
    int r0 = R0 + 2 * tr, r1 = r0 + 1;
    int c0 = tc * CPT;
    bool ok0 = r0 < NN, ok1 = r1 < NN;
    const float4* X4 = (const float4*)X;
    const float4 z4 = make_float4(0.f, 0.f, 0.f, 0.f);

    float acc[2][CPT];
#pragma unroll
    for (int rr = 0; rr < 2; ++rr)
#pragma unroll
        for (int j = 0; j < CPT; ++j) acc[rr][j] = 0.f;

#pragma unroll 2
    for (int k4 = 0; k4 < KF4; ++k4) {
        float4 xa = ok0 ? X4[(size_t)r0 * KF4 + k4] : z4;
        float4 xb = ok1 ? X4[(size_t)r1 * KF4 + k4] : z4;
        float ar[4] = {xa.x, xa.y, xa.z, xa.w};
        float br[4] = {xb.x, xb.y, xb.z, xb.w};
#pragma unroll
        for (int j = 0; j < 4; ++j) {
            float va = ar[j], vb = br[j];
#pragma unroll
            for (int q = 0; q < CPT / 4; ++q) {
                float4 wv = *(const float4*)&w[(4 * k4 + j) * NC + c0 + 4 * q];
                acc[0][q*4+0] = fmaf(va, wv.x, acc[0][q*4+0]);
                acc[0][q*4+1] = fmaf(va, wv.y, acc[0][q*4+1]);
                acc[0][q*4+2] = fmaf(va, wv.z, acc[0][q*4+2]);
                acc[0][q*4+3] = fmaf(va, wv.w, acc[0][q*4+3]);
                acc[1][q*4+0] = fmaf(vb, wv.x, acc[1][q*4+0]);
                acc[1][q*4+1] = fmaf(vb, wv.y, acc[1][q*4+1]);
                acc[1][q*4+2] = fmaf(vb, wv.z, acc[1][q*4+2]);
                acc[1][q*4+3] = fmaf(vb, wv.w, acc[1][q*4+3]);
            }
        }
    }
#pragma unroll
    for (int rr = 0; rr < 2; ++rr) {
        int gr = r0 + rr;
        if (gr >= NN) continue;
#pragma unroll
        for (int q = 0; q < CPT / 4; ++q) {
            __half2 p0 = __floats2half2_rn(acc[rr][q*4+0], acc[rr][q*4+1]);
            __half2 p1 = __floats2half2_rn(acc[rr][q*4+2], acc[rr][q*4+3]);
            half4 hv; hv.lo = p0; hv.hi = p1;
            *(half4*)(Hh + (size_t)gr * NC + c0 + 4 * q) = hv;
        }
    }
}

// Per-bucket sort, segment-gather version. Block b pulls bucket b's 391
// segments from the block-major runs (random-line READS), then proceeds
// identically to the proven bsort: key count/scan, rowinfo/dinv, windowed
// scatter to srcsort.
__global__ __launch_bounds__(256) void
k_bsort2(const int* __restrict__ runs, const unsigned int* __restrict__ seg,
         int* __restrict__ srcsort, unsigned int* __restrict__ rowinfo,
         float* __restrict__ dinv) {
    __shared__ int stage[CAP];          // 16 KB
    __shared__ int cnt[NKEY];           // 4 KB
    __shared__ int tsum[256];
    int tid = threadIdx.x, b = blockIdx.x;

    // gather segments: thread t handles partition blocks t and t+256
    unsigned int s0 = (tid < PART_G) ? seg[(size_t)tid * NBUCK + b] : 0u;
    unsigned int s1 = (tid + 256 < PART_G) ? seg[(size_t)(tid + 256) * NBUCK + b] : 0u;
    int l0 = (int)(s0 & 511u), l1 = (int)(s1 & 511u);
    int mylen = l0 + l1;
    tsum[tid] = mylen;
    __syncthreads();
    for (int off = 1; off < 256; off <<= 1) {
        int v = (tid >= off) ? tsum[tid - off] : 0;
        __syncthreads();
        tsum[tid] += v;
        __syncthreads();
    }
    int wbase = tsum[tid] - mylen;
    int sz = tsum[255];
    {
        const int* p = runs + (size_t)tid * RUNW + (s0 >> 9);
        for (int i = 0; i < l0; ++i) stage[wbase + i] = p[i];
        p = runs + (size_t)(tid + 256) * RUNW + (s1 >> 9);
        for (int i = 0; i < l1; ++i) stage[wbase + l0 + i] = p[i];
    }
    for (int i = tid; i < NKEY; i += 256) cnt[i] = 0;
    __syncthreads();

    // ---- identical to proven bsort from here ----
    for (int i = tid; i < sz; i += 256) {
        int w = stage[i];
        int key = ((w >> PBITS) << CHB) | ((w & PMASK) >> CHS);
        atomicAdd(&cnt[key], 1);
    }
    __syncthreads();
    int k0 = tid * 4;
    int c0 = cnt[k0], c1 = cnt[k0 + 1], c2 = cnt[k0 + 2], c3 = cnt[k0 + 3];
    int loc = c0 + c1 + c2 + c3;
    tsum[tid] = loc;
    __syncthreads();
    for (int off = 1; off < 256; off <<= 1) {
        int v = (tid >= off) ? tsum[tid - off] : 0;
        __syncthreads();
        tsum[tid] += v;
        __syncthreads();
    }
    int base = tsum[tid] - loc;
    cnt[k0]     = base;
    cnt[k0 + 1] = base + c0;
    cnt[k0 + 2] = base + c0 + c1;
    cnt[k0 + 3] = base + c0 + c1 + c2;
    __syncthreads();
    int e0 = b * CAP;
    if (tid < NPB) {
        int node = b * NPB + tid;
        int rs = cnt[tid << CHB];
        int re = (tid == NPB - 1) ? sz : cnt[(tid + 1) << CHB];
        if (node < NN) {
            rowinfo[node] = ((unsigned int)(e0 + rs) << 10) | (unsigned int)(re - rs);
            dinv[node] = rsqrtf((float)(re - rs + 1));   // +1 self-loop
        }
    }
    __syncthreads();
    for (int i = tid; i < sz; i += 256) {
        int w = stage[i];
        int key = ((w >> PBITS) << CHB) | ((w & PMASK) >> CHS);
        int p = atomicAdd(&cnt[key], 1);
        srcsort[e0 + p] = w & PMASK;
    }
}

// Fused layer-1 aggregation + relu/b1 + GEMM2 + dinv. 128-row tile, 256 thr
// (r12 geometry). Hh UNSCALED: per-edge dinv[src] folded into the batch mask
// multiplier (validated r17, absmax bit-identical); self term x dinv[r].
__global__ __launch_bounds__(256) void
k_fused48(const __half* __restrict__ Hh, const unsigned int* __restrict__ rowinfo,
          const int* __restrict__ srcsort, const float* __restrict__ dinv,
          const float* __restrict__ b1, const float* __restrict__ W2,
          __half* __restrict__ Hh2) {
    constexpr int ROWS = 128, XS = 49;
    __shared__ float Xs[ROWS * XS];      // 25088 B
    __shared__ float w2[48 * 32];        // 6144 B
    __shared__ float bb[48];
    int tid = threadIdx.x;
    int R0 = blockIdx.x * ROWS;
    for (int i = tid; i < 48 * 32; i += 256) w2[i] = W2[i];
    if (tid < 48) bb[tid] = b1[tid];
    __syncthreads();

    // ---- phase 1: aggregate into Xs (3 (row,chunk) items per thread) ----
    for (int t = tid; t < ROWS * 6; t += 256) {
        int lr = t / 6, q = t - lr * 6;
        int r = R0 + lr;
        if (r >= NN) continue;
        float dself = dinv[r];
        half8 sv = *(const half8*)(Hh + (size_t)r * 48 + 8 * q);   // self-loop
        float2 f0 = __half22float2(sv.a), f1 = __half22float2(sv.b);
        float2 f2 = __half22float2(sv.c), f3 = __half22float2(sv.d);
        float a0 = f0.x * dself, a1 = f0.y * dself;
        float a2 = f1.x * dself, a3 = f1.y * dself;
        float a4 = f2.x * dself, a5 = f2.y * dself;
        float a6 = f3.x * dself, a7 = f3.y * dself;
        unsigned int rp = rowinfo[r];
        int e0 = rp >> 10, e1 = e0 + (int)(rp & 1023);
        for (int e = e0; e < e1; e += UN) {
            int ss[UN]; float ms[UN];
#pragma unroll
            for (int u = 0; u < UN; ++u) {
                int ee = e + u;
                bool ok = ee < e1;
                ss[u] = srcsort[ok ? ee : e0];
                ms[u] = ok ? 1.f : 0.f;
            }
            half8 vv[UN]; float dv[UN];
#pragma unroll
            for (int u = 0; u < UN; ++u) {
                vv[u] = *(const half8*)(Hh + (size_t)ss[u] * 48 + 8 * q);
                dv[u] = dinv[ss[u]];
            }
#pragma unroll
            for (int u = 0; u < UN; ++u) {
                float2 g0 = __half22float2(vv[u].a), g1 = __half22float2(vv[u].b);
                float2 g2 = __half22float2(vv[u].c), g3 = __half22float2(vv[u].d);
                float m = ms[u] * dv[u];
                a0 = fmaf(g0.x, m, a0); a1 = fmaf(g0.y, m, a1);
                a2 = fmaf(g1.x, m, a2); a3 = fmaf(g1.y, m, a3);
                a4 = fmaf(g2.x, m, a4); a5 = fmaf(g2.y, m, a5);
                a6 = fmaf(g3.x, m, a6); a7 = fmaf(g3.y, m, a7);
            }
        }
        float d = dself;
        float* xr = &Xs[lr * XS + 8 * q];
        const float* bf = &bb[8 * q];
        xr[0] = fmaxf(fmaf(a0, d, bf[0]), 0.f);
        xr[1] = fmaxf(fmaf(a1, d, bf[1]), 0.f);
        xr[2] = fmaxf(fmaf(a2, d, bf[2]), 0.f);
        xr[3] = fmaxf(fmaf(a3, d, bf[3]), 0.f);
        xr[4] = fmaxf(fmaf(a4, d, bf[4]), 0.f);
        xr[5] = fmaxf(fmaf(a5, d, bf[5]), 0.f);
        xr[6] = fmaxf(fmaf(a6, d, bf[6]), 0.f);
        xr[7] = fmaxf(fmaf(a7, d, bf[7]), 0.f);
    }
    __syncthreads();

    // ---- phase 2: Xs[128,48] @ W2[48,32] -> Hh2 (fp16); 2 rows x 8 cols ----
    int tc = tid & 3, tr = tid >> 2;
    int r0l = 2 * tr, c0 = tc * 8;
    float acc[2][8];
#pragma unroll
    for (int rr = 0; rr < 2; ++rr)
#pragma unroll
        for (int j = 0; j < 8; ++j) acc[rr][j] = 0.f;
#pragma unroll 4
    for (int k = 0; k < 48; ++k) {
        float x0 = Xs[r0l * XS + k];
        float x1 = Xs[(r0l + 1) * XS + k];
        float4 wv0 = *(const float4*)&w2[k * 32 + c0];
        float4 wv1 = *(const float4*)&w2[k * 32 + c0 + 4];
        acc[0][0] = fmaf(x0, wv0.x, acc[0][0]); acc[0][1] = fmaf(x0, wv0.y, acc[0][1]);
        acc[0][2] = fmaf(x0, wv0.z, acc[0][2]); acc[0][3] = fmaf(x0, wv0.w, acc[0][3]);
        acc[0][4] = fmaf(x0, wv1.x, acc[0][4]); acc[0][5] = fmaf(x0, wv1.y, acc[0][5]);
        acc[0][6] = fmaf(x0, wv1.z, acc[0][6]); acc[0][7] = fmaf(x0, wv1.w, acc[0][7]);
        acc[1][0] = fmaf(x1, wv0.x, acc[1][0]); acc[1][1] = fmaf(x1, wv0.y, acc[1][1]);
        acc[1][2] = fmaf(x1, wv0.z, acc[1][2]); acc[1][3] = fmaf(x1, wv0.w, acc[1][3]);
        acc[1][4] = fmaf(x1, wv1.x, acc[1][4]); acc[1][5] = fmaf(x1, wv1.y, acc[1][5]);
        acc[1][6] = fmaf(x1, wv1.z, acc[1][6]); acc[1][7] = fmaf(x1, wv1.w, acc[1][7]);
    }
#pragma unroll
    for (int rr = 0; rr < 2; ++rr) {
        int gr = R0 + r0l + rr;
        if (gr >= NN) continue;
        float d = dinv[gr];
        __half2 p0 = __floats2half2_rn(acc[rr][0] * d, acc[rr][1] * d);
        __half2 p1 = __floats2half2_rn(acc[rr][2] * d, acc[rr][3] * d);
        __half2 p2 = __floats2half2_rn(acc[rr][4] * d, acc[rr][5] * d);
        __half2 p3 = __floats2half2_rn(acc[rr][6] * d, acc[rr][7] * d);
        half8 hv; hv.a = p0; hv.b = p1; hv.c = p2; hv.d = p3;
        *(half8*)(Hh2 + (size_t)gr * 32 + c0) = hv;
    }
}

// Layer-2 aggregation: out[i,:] = dinv[i]*(Hh2[i,:] + sum Hh2[src,:]) + b2
// Masked full-width UN-batches. UNCHANGED (Hh2 remains pre-scaled).
template <int NC>
__global__ void k_agg(const __half* __restrict__ Hh, const unsigned int* __restrict__ rowinfo,
                      const int* __restrict__ srcsort, const float* __restrict__ dinv,
                      const float* __restrict__ bias, float* __restrict__ out) {
    constexpr int Q = NC / 8;
    int idx = blockIdx.x * blockDim.x + threadIdx.x;
    if (idx >= NN * Q) return;
    int r = idx / Q, q = idx - r * Q;
    half8 sv = *(const half8*)(Hh + (size_t)r * NC + 8 * q);
    float2 f0 = __half22float2(sv.a), f1 = __half22float2(sv.b);
    float2 f2 = __half22float2(sv.c), f3 = __half22float2(sv.d);
    float a0 = f0.x, a1 = f0.y, a2 = f1.x, a3 = f1.y;
    float a4 = f2.x, a5 = f2.y, a6 = f3.x, a7 = f3.y;
    unsigned int rp = rowinfo[r];
    int e0 = rp >> 10, e1 = e0 + (int)(rp & 1023);
    for (int e = e0; e < e1; e += UN) {
        int ss[UN]; float ms[UN];
#pragma unroll
        for (int u = 0; u < UN; ++u) {
            int ee = e + u;
            bool ok = ee < e1;
            ss[u] = srcsort[ok ? ee : e0];
            ms[u] = ok ? 1.f : 0.f;
        }
        half8 vv[UN];
#pragma unroll
        for (int u = 0; u < UN; ++u)
            vv[u] = *(const half8*)(Hh + (size_t)ss[u] * NC + 8 * q);
#pragma unroll
        for (int u = 0; u < UN; ++u) {
            float2 g0 = __half22float2(vv[u].a), g1 = __half22float2(vv[u].b);
            float2 g2 = __half22float2(vv[u].c), g3 = __half22float2(vv[u].d);
            float m = ms[u];
            a0 = fmaf(g0.x, m, a0); a1 = fmaf(g0.y, m, a1);
            a2 = fmaf(g1.x, m, a2); a3 = fmaf(g1.y, m, a3);
            a4 = fmaf(g2.x, m, a4); a5 = fmaf(g2.y, m, a5);
            a6 = fmaf(g3.x, m, a6); a7 = fmaf(g3.y, m, a7);
        }
    }
    float d = dinv[r];
    const float4* b4 = (const float4*)bias;
    float4 bv0 = b4[2 * q], bv1 = b4[2 * q + 1];
    a0 = fmaf(a0, d, bv0.x); a1 = fmaf(a1, d, bv0.y);
    a2 = fmaf(a2, d, bv0.z); a3 = fmaf(a3, d, bv0.w);
    a4 = fmaf(a4, d, bv1.x); a5 = fmaf(a5, d, bv1.y);
    a6 = fmaf(a6, d, bv1.z); a7 = fmaf(a7, d, bv1.w);
    float4* o4 = (float4*)(out + (size_t)r * NC + 8 * q);
    o4[0] = make_float4(a0, a1, a2, a3);
    o4[1] = make_float4(a4, a5, a6, a7);
}

extern "C" void kernel_launch(void* const* d_in, const int* in_sizes, int n_in,
                              void* d_out, int out_size, void* d_ws, size_t ws_size,
                              hipStream_t stream) {
    const float* x  = (const float*)d_in[0];
    const int*   ei = (const int*)d_in[1];   // [2,NE] int32
    const float* W1 = (const float*)d_in[2];
    const float* b1 = (const float*)d_in[3];
    const float* W2 = (const float*)d_in[4];
    const float* b2 = (const float*)d_in[5];
    float* out = (float*)d_out;

    const int* src = ei;
    const int* dst = ei + NE;

    char* p = (char*)d_ws;
    auto take = [&](size_t elems) { void* q = p; p += ((elems * 4 + 255) & ~255ull); return q; };
    unsigned int* rowinfo = (unsigned int*)take(NN);
    float*        dinv    = (float*)take(NN);
    int*          srcsort = (int*)take((size_t)NBUCK * CAP);   // bucket-padded
    __half*       Hh      = (__half*)take((size_t)NN * 24);    // NN*48 halves
    unsigned int* seg     = (unsigned int*)take((size_t)PART_G * NBUCK);  // 1.2 MB
    int*          runs    = (int*)take((size_t)PART_G * RUNW); // 6.4 MB, dead after bsort2
    __half*       Hh2     = (__half*)runs;                     // reuse (NN*32 halves = 6.4 MB)

    const int B = 256;
    // --- merged: local-sort partition (all writes coalesced) + GEMM1 ---
    k_lsortgemm<<<PART_G + GEMM_G, PART_B, 0, stream>>>(src, dst, runs, seg, x, W1, Hh);
    // --- per-bucket sort via segment gather (random READS, not writes) ---
    k_bsort2<<<NBUCK, 256, 0, stream>>>(runs, seg, srcsort, rowinfo, dinv);
    // --- fused: layer-1 aggregation (per-edge dinv) + relu/b1 + GEMM2 ---
    k_fused48<<<GB, 256, 0, stream>>>(Hh, rowinfo, srcsort, dinv, b1, W2, Hh2);
    // --- layer-2 aggregation (+b2) ---
    k_agg<32><<<(NN * 4 + B - 1) / B, B, 0, stream>>>(Hh2, rowinfo, srcsort, dinv, b2, out);
}